// Round 3
// baseline (247.717 us; speedup 1.0000x reference)
//
#include <hip/hip_runtime.h>
#include <hip/hip_bf16.h>

typedef __bf16 bf16x8 __attribute__((ext_vector_type(8)));
typedef __bf16 bf16x4 __attribute__((ext_vector_type(4)));
typedef float floatx4 __attribute__((ext_vector_type(4)));

#define XROW 136   // padded LDS row stride (bf16 elems)

// Grid 2048 = (half 2) x (b 128) x (i 8). Block: 256 thr, 4 waves.
// Block computes 128 rows x 128 outputs of channel i, batch b.
// A = W (per-wave 32-o slice, fragments in VGPRs, loaded direct from global),
// B = X (bf16 in LDS, staged with per-lane-coalesced 1KB/instr loads).
// Single barrier; epilogue stores are global_store_dwordx4.
__global__ __launch_bounds__(256, 4)
void mcsl_kernel(const float* __restrict__ x, const float* __restrict__ W,
                 const float* __restrict__ bias, float* __restrict__ y)
{
    __shared__ __align__(16) __bf16 Xlds[128 * XROW];

    const int tid  = threadIdx.x;
    const int i    = blockIdx.x & 7;           // channel -> W L2 locality
    const int b    = (blockIdx.x >> 3) & 127;  // batch
    const int half = blockIdx.x >> 10;         // which 128-row half

    const float* xb = x + (size_t)(b * 64 + i * 8) * 4096 + half * 16384;
    float*       yb = y + (size_t)(b * 64 + i * 8) * 4096 + half * 16384;

    const int lane = tid & 63;
    const int wv   = tid >> 6;    // wave -> o-slice [wv*32, wv*32+32)
    const int nrow = lane & 15;
    const int quad = lane >> 4;

    const float4* xsrc = (const float4*)xb;

    // ---- X batch 0 (rows 0..63): lane-coalesced, 1KB per instruction ----
    float4 xf0[8];
    #pragma unroll
    for (int j = 0; j < 8; ++j) xf0[j] = xsrc[j * 256 + tid];

    // ---- W fragments direct from global (L2-hot: 64KB per channel) ----
    // frag(ot,ks): lane = W[i][wv*32 + ot*16 + nrow][ks*32 + quad*8 .. +8)
    const float* wb = W + (size_t)i * 16384 + (wv * 32 + nrow) * 128 + quad * 8;
    float4 wf[8][2];
    #pragma unroll
    for (int ot = 0; ot < 2; ++ot)
        #pragma unroll
        for (int ks = 0; ks < 4; ++ks) {
            const float* p = wb + ot * 2048 + ks * 32;
            wf[ot * 4 + ks][0] = *(const float4*)p;
            wf[ot * 4 + ks][1] = *(const float4*)(p + 4);
        }

    // bias: lane needs bias[i*128 + wv*32 + ot*16 + quad*4 + r]
    floatx4 bfrag[2];
    #pragma unroll
    for (int ot = 0; ot < 2; ++ot)
        bfrag[ot] = *(const floatx4*)(bias + i * 128 + wv * 32 + ot * 16 + quad * 4);

    // ---- convert + write X batch 0 to LDS ----
    #pragma unroll
    for (int j = 0; j < 8; ++j) {
        int idx = j * 256 + tid;            // float4 index: row = idx>>5
        int row = idx >> 5, c4 = (idx & 31) * 4;
        bf16x4 v;
        v[0] = (__bf16)xf0[j].x; v[1] = (__bf16)xf0[j].y;
        v[2] = (__bf16)xf0[j].z; v[3] = (__bf16)xf0[j].w;
        *(bf16x4*)&Xlds[row * XROW + c4] = v;
    }

    // ---- X batch 1 loads (rows 64..127) ----
    float4 xf1[8];
    #pragma unroll
    for (int j = 0; j < 8; ++j) xf1[j] = xsrc[(j + 8) * 256 + tid];

    // ---- convert W -> bf16 fragments (frees wf regs) ----
    bf16x8 wfrag[8];
    #pragma unroll
    for (int f = 0; f < 8; ++f) {
        bf16x8 v;
        v[0] = (__bf16)wf[f][0].x; v[1] = (__bf16)wf[f][0].y;
        v[2] = (__bf16)wf[f][0].z; v[3] = (__bf16)wf[f][0].w;
        v[4] = (__bf16)wf[f][1].x; v[5] = (__bf16)wf[f][1].y;
        v[6] = (__bf16)wf[f][1].z; v[7] = (__bf16)wf[f][1].w;
        wfrag[f] = v;
    }

    // ---- convert + write X batch 1 ----
    #pragma unroll
    for (int j = 0; j < 8; ++j) {
        int idx = (j + 8) * 256 + tid;
        int row = idx >> 5, c4 = (idx & 31) * 4;
        bf16x4 v;
        v[0] = (__bf16)xf1[j].x; v[1] = (__bf16)xf1[j].y;
        v[2] = (__bf16)xf1[j].z; v[3] = (__bf16)xf1[j].w;
        *(bf16x4*)&Xlds[row * XROW + c4] = v;
    }
    __syncthreads();   // the only barrier

    // ---- compute: 8 row-tiles; per tile 4 LDS reads, 8 MFMA, 2 stores ----
    #pragma unroll
    for (int rt = 0; rt < 8; ++rt) {
        bf16x8 xfr[4];
        #pragma unroll
        for (int ks = 0; ks < 4; ++ks)
            xfr[ks] = *(const bf16x8*)&Xlds[(rt * 16 + nrow) * XROW + ks * 32 + quad * 8];

        floatx4 acc0 = {0.f, 0.f, 0.f, 0.f};
        floatx4 acc1 = {0.f, 0.f, 0.f, 0.f};
        #pragma unroll
        for (int ks = 0; ks < 4; ++ks) {
            acc0 = __builtin_amdgcn_mfma_f32_16x16x32_bf16(wfrag[ks],     xfr[ks], acc0, 0, 0, 0);
            acc1 = __builtin_amdgcn_mfma_f32_16x16x32_bf16(wfrag[4 + ks], xfr[ks], acc1, 0, 0, 0);
        }

        // D: col(lane&15) = batch row in tile, row(quad*4+r) = o offset
        // lane stores y[rt*16+nrow][wv*32 + ot*16 + quad*4 .. +4) : dwordx4
        float* yrow = yb + (size_t)(rt * 16 + nrow) * 128 + wv * 32 + quad * 4;
        *(floatx4*)yrow        = acc0 + bfrag[0];
        *(floatx4*)(yrow + 16) = acc1 + bfrag[1];
    }
}

extern "C" void kernel_launch(void* const* d_in, const int* in_sizes, int n_in,
                              void* d_out, int out_size, void* d_ws, size_t ws_size,
                              hipStream_t stream) {
    const float* x = (const float*)d_in[0];
    const float* W = (const float*)d_in[1];
    const float* b = (const float*)d_in[2];
    float* y = (float*)d_out;
    dim3 grid(2048), block(256);
    hipLaunchKernelGGL(mcsl_kernel, grid, block, 0, stream, x, W, b, y);
}